// Round 17
// baseline (602.022 us; speedup 1.0000x reference)
//
#include <hip/hip_runtime.h>
#include <cstddef>
#include <cstdint>

#define NN 100000
#define NE 3200000
#define D  128
#define NB 782          // ceil(NN/128) dst-buckets of 128 nodes
#define BSH 7
#define NPB 512         // partition blocks
#define CHUNK 6250      // ceil(NE/NPB)
#define BCAP 4608       // fixed bucket stride: mean 4092 + 8 sigma

typedef short v8s __attribute__((ext_vector_type(8)));
typedef float v4f __attribute__((ext_vector_type(4)));

// ---------------- bf16 helpers ----------------

__device__ __forceinline__ unsigned short f2bf(float f) {
  uint32_t u = __float_as_uint(f);
  uint32_t r = u + 0x7fff + ((u >> 16) & 1);   // RNE
  return (unsigned short)(r >> 16);
}
__device__ __forceinline__ float bf_lo(uint32_t v) {
  return __uint_as_float(v << 16);
}
__device__ __forceinline__ float bf_hi(uint32_t v) {
  return __uint_as_float(v & 0xffff0000u);
}

// ---------------- graph prep (R9-proven, exact) ----------------

__global__ __launch_bounds__(256) void kb_part2(const int* __restrict__ src,
                                                const int* __restrict__ dst,
                                                int* __restrict__ gcur,
                                                uint32_t* __restrict__ ebuf) {
  __shared__ int h[NB];
  __shared__ int cur[NB];
  for (int i = threadIdx.x; i < NB; i += 256) h[i] = 0;
  __syncthreads();
  int lo = blockIdx.x * CHUNK, hi = lo + CHUNK;
  if (hi > NE) hi = NE;
  for (int e = lo + threadIdx.x; e < hi; e += 256)
    atomicAdd(&h[dst[e] >> BSH], 1);
  __syncthreads();
  for (int i = threadIdx.x; i < NB; i += 256)
    cur[i] = h[i] ? atomicAdd(&gcur[i], h[i]) : 0;
  __syncthreads();
  for (int e = lo + threadIdx.x; e < hi; e += 256) {
    int s = src[e], d = dst[e];
    int b = d >> BSH;
    int p = atomicAdd(&cur[b], 1);
    if (p < BCAP)  // deterministic input: never triggers (8-sigma headroom)
      ebuf[(size_t)b * BCAP + p] = ((uint32_t)s << BSH) | (uint32_t)(d & 127);
  }
}

__global__ __launch_bounds__(256) void kb_build(const uint32_t* __restrict__ ebuf,
                                                const int* __restrict__ gcur,
                                                int* __restrict__ row_off,
                                                int* __restrict__ row_end,
                                                float* __restrict__ dinv,
                                                int* __restrict__ col) {
  int b = blockIdx.x;
  __shared__ int h[128];
  __shared__ int s[128];
  __shared__ int cur[128];
  if (threadIdx.x < 128) h[threadIdx.x] = 0;
  __syncthreads();
  const uint32_t* eb = ebuf + (size_t)b * BCAP;
  int cnt = gcur[b];
  for (int e = threadIdx.x; e < cnt; e += 256)
    atomicAdd(&h[eb[e] & 127], 1);
  __syncthreads();
  int v = (threadIdx.x < 128) ? h[threadIdx.x] : 0;
  if (threadIdx.x < 128) s[threadIdx.x] = v;
  __syncthreads();
  for (int d = 1; d < 128; d <<= 1) {
    int t = (threadIdx.x < 128 && threadIdx.x >= d) ? s[threadIdx.x - d] : 0;
    __syncthreads();
    if (threadIdx.x < 128) s[threadIdx.x] += t;
    __syncthreads();
  }
  if (threadIdx.x < 128) {
    int ro = b * BCAP + s[threadIdx.x] - v;
    cur[threadIdx.x] = ro;
    int node = b * 128 + threadIdx.x;
    if (node < NN) {
      row_off[node] = ro;
      row_end[node] = ro + v;
      dinv[node] = rsqrtf((float)(v + 1));  // +1 self-loop
    }
  }
  __syncthreads();
  for (int e = threadIdx.x; e < cnt; e += 256) {
    uint32_t p = eb[e];
    int pos = atomicAdd(&cur[p & 127], 1);
    col[pos] = (int)(p >> BSH);
  }
}

// ---------------- weight prep (+ gcur zeroing folded in) ----------------

__global__ void k_wt3z(const float* __restrict__ W1, const float* __restrict__ W2,
                       const float* __restrict__ W3, unsigned short* __restrict__ wt,
                       int* __restrict__ gcur) {
  int idx = blockIdx.x * 256 + threadIdx.x;  // 0..49151
  if (idx < NB) gcur[idx] = 0;
  if (idx >= 3 * 16384) return;
  int m = idx >> 14, rem = idx & 16383;
  int k = rem >> 7, c = rem & 127;
  const float* W = (m == 0) ? W1 : (m == 1) ? W2 : W3;
  wt[m * 16384 + c * 128 + k] = f2bf(W[rem]);
}

// ---------------- MFMA GEMM for layer 1 (f32 x input; R6-proven math) ----------------

__global__ __launch_bounds__(128) void k_gemm2(const float* __restrict__ A,
                                               const unsigned short* __restrict__ wt,
                                               const float* __restrict__ dinv,
                                               unsigned short* __restrict__ C) {
  const int wave = threadIdx.x >> 6;
  const int lane = threadIdx.x & 63;
  const int row0 = blockIdx.x * 128 + wave * 64;
  const int rl = lane & 15;
  const int kg = lane >> 4;

  v4f acc[4][8];
#pragma unroll
  for (int t = 0; t < 4; ++t)
#pragma unroll
    for (int ct = 0; ct < 8; ++ct) acc[t][ct] = (v4f){0.f, 0.f, 0.f, 0.f};

  union U { uint4 u; v8s v; unsigned short us[8]; };

#pragma unroll
  for (int ks = 0; ks < 4; ++ks) {
    U a[4];
#pragma unroll
    for (int t = 0; t < 4; ++t) {
      int r = row0 + t * 16 + rl;
      if (r >= NN) r = NN - 1;   // clamp; stores guarded
      const float* ap = A + (size_t)r * D + ks * 32 + kg * 8;
      float4 l4 = *(const float4*)ap;
      float4 h4 = *(const float4*)(ap + 4);
      a[t].us[0] = f2bf(l4.x); a[t].us[1] = f2bf(l4.y);
      a[t].us[2] = f2bf(l4.z); a[t].us[3] = f2bf(l4.w);
      a[t].us[4] = f2bf(h4.x); a[t].us[5] = f2bf(h4.y);
      a[t].us[6] = f2bf(h4.z); a[t].us[7] = f2bf(h4.w);
    }
#pragma unroll
    for (int ct = 0; ct < 8; ++ct) {
      U b;
      b.u = *(const uint4*)(wt + (size_t)(ct * 16 + rl) * 128 + ks * 32 + kg * 8);
#pragma unroll
      for (int t = 0; t < 4; ++t)
        acc[t][ct] =
            __builtin_amdgcn_mfma_f32_16x16x32_bf16(a[t].v, b.v, acc[t][ct], 0, 0, 0);
    }
  }

#pragma unroll
  for (int t = 0; t < 4; ++t) {
#pragma unroll
    for (int i = 0; i < 4; ++i) {
      int row = row0 + t * 16 + kg * 4 + i;
      if (row < NN) {
        float dv = dinv[row];
#pragma unroll
        for (int ct = 0; ct < 8; ++ct)
          C[(size_t)row * D + ct * 16 + rl] = f2bf(dv * acc[t][ct][i]);
      }
    }
  }
}

// ---------------- split-gather macros ----------------
// Lanes 0-31 accumulate node gA's column-half h, lanes 32-63 node gB's.
// Per-output-column term order (self, then CSR edge order) identical to
// R14/R16 -> absmax bit-exact. Per pass the tu working set is 12.8MB.

#define DUAL8(eAi, eBi)                                                      \
  {                                                                          \
    int sA0 = col[eAi],     sA1 = col[eAi + 1], sA2 = col[eAi + 2],          \
        sA3 = col[eAi + 3], sA4 = col[eAi + 4], sA5 = col[eAi + 5],          \
        sA6 = col[eAi + 6], sA7 = col[eAi + 7];                              \
    int sB0 = col[eBi],     sB1 = col[eBi + 1], sB2 = col[eBi + 2],          \
        sB3 = col[eBi + 3], sB4 = col[eBi + 4], sB5 = col[eBi + 5],          \
        sB6 = col[eBi + 6], sB7 = col[eBi + 7];                              \
    uint32_t v0 = tu[(size_t)(lo32 ? sA0 : sB0) * 64 + h32l];                \
    uint32_t v1 = tu[(size_t)(lo32 ? sA1 : sB1) * 64 + h32l];                \
    uint32_t v2 = tu[(size_t)(lo32 ? sA2 : sB2) * 64 + h32l];                \
    uint32_t v3 = tu[(size_t)(lo32 ? sA3 : sB3) * 64 + h32l];                \
    uint32_t v4 = tu[(size_t)(lo32 ? sA4 : sB4) * 64 + h32l];                \
    uint32_t v5 = tu[(size_t)(lo32 ? sA5 : sB5) * 64 + h32l];                \
    uint32_t v6 = tu[(size_t)(lo32 ? sA6 : sB6) * 64 + h32l];                \
    uint32_t v7 = tu[(size_t)(lo32 ? sA7 : sB7) * 64 + h32l];                \
    q0 += bf_lo(v0); q1 += bf_hi(v0);                                        \
    q0 += bf_lo(v1); q1 += bf_hi(v1);                                        \
    q0 += bf_lo(v2); q1 += bf_hi(v2);                                        \
    q0 += bf_lo(v3); q1 += bf_hi(v3);                                        \
    q0 += bf_lo(v4); q1 += bf_hi(v4);                                        \
    q0 += bf_lo(v5); q1 += bf_hi(v5);                                        \
    q0 += bf_lo(v6); q1 += bf_hi(v6);                                        \
    q0 += bf_lo(v7); q1 += bf_hi(v7);                                        \
  }

#define DRAIN8(e0, pred)                                                     \
  {                                                                          \
    int s0 = col[e0], s1 = col[e0 + 1], s2 = col[e0 + 2], s3 = col[e0 + 3],  \
        s4 = col[e0 + 4], s5 = col[e0 + 5], s6 = col[e0 + 6], s7 = col[e0 + 7];\
    uint32_t v0 = tu[(size_t)s0 * 64 + h32l];                                \
    uint32_t v1 = tu[(size_t)s1 * 64 + h32l];                                \
    uint32_t v2 = tu[(size_t)s2 * 64 + h32l];                                \
    uint32_t v3 = tu[(size_t)s3 * 64 + h32l];                                \
    uint32_t v4 = tu[(size_t)s4 * 64 + h32l];                                \
    uint32_t v5 = tu[(size_t)s5 * 64 + h32l];                                \
    uint32_t v6 = tu[(size_t)s6 * 64 + h32l];                                \
    uint32_t v7 = tu[(size_t)s7 * 64 + h32l];                                \
    q0 += (pred) ? bf_lo(v0) : 0.f; q1 += (pred) ? bf_hi(v0) : 0.f;          \
    q0 += (pred) ? bf_lo(v1) : 0.f; q1 += (pred) ? bf_hi(v1) : 0.f;          \
    q0 += (pred) ? bf_lo(v2) : 0.f; q1 += (pred) ? bf_hi(v2) : 0.f;          \
    q0 += (pred) ? bf_lo(v3) : 0.f; q1 += (pred) ? bf_hi(v3) : 0.f;          \
    q0 += (pred) ? bf_lo(v4) : 0.f; q1 += (pred) ? bf_hi(v4) : 0.f;          \
    q0 += (pred) ? bf_lo(v5) : 0.f; q1 += (pred) ? bf_hi(v5) : 0.f;          \
    q0 += (pred) ? bf_lo(v6) : 0.f; q1 += (pred) ? bf_hi(v6) : 0.f;          \
    q0 += (pred) ? bf_lo(v7) : 0.f; q1 += (pred) ? bf_hi(v7) : 0.f;          \
  }

#define DRAIN1(e0, pred)                                                     \
  {                                                                          \
    uint32_t v = tu[(size_t)col[e0] * 64 + h32l];                            \
    q0 += (pred) ? bf_lo(v) : 0.f; q1 += (pred) ? bf_hi(v) : 0.f;            \
  }

// produces q0,q1 = per-lane column pair of this lane's node & half
#define GATHER_HALF()                                                        \
  float q0, q1;                                                              \
  {                                                                          \
    uint32_t sv = tu[(size_t)gMy * 64 + h32l];                               \
    q0 = bf_lo(sv); q1 = bf_hi(sv);                                          \
    int eA = roA, eB = roB;                                                  \
    while (eA + 8 <= endA && eB + 8 <= endB) {                               \
      DUAL8(eA, eB);                                                         \
      eA += 8; eB += 8;                                                      \
    }                                                                        \
    for (; eA + 8 <= endA; eA += 8) DRAIN8(eA, lo32);                        \
    for (; eA < endA; ++eA) DRAIN1(eA, lo32);                                \
    for (; eB + 8 <= endB; eB += 8) DRAIN8(eB, !lo32);                       \
    for (; eB < endB; ++eB) DRAIN1(eB, !lo32);                               \
  }

// ---------------- fused agg + GEMV, barrier-free, split-gather ----------------

__global__ __launch_bounds__(128) void k_aggf(
    const uint32_t* __restrict__ tu, const int* __restrict__ row_off,
    const int* __restrict__ row_end, const int* __restrict__ col,
    const float* __restrict__ dinv, const float* __restrict__ bias,
    const unsigned short* __restrict__ wt, unsigned short* __restrict__ t_out) {
  const int wave = threadIdx.x >> 6;
  const int lane = threadIdx.x & 63;
  const bool lo32 = lane < 32;
  const int l31 = lane & 31;
  const int base = blockIdx.x * 32 + wave * 16;  // this wave's 16 nodes

  __shared__ uint32_t lds[2][16 * 64];  // 4KB per wave, private slices
  uint32_t* lw = lds[wave];

#pragma unroll 1
  for (int p = 0; p < 8; ++p) {
    int gA = base + 2 * p;
    int gB = gA + 1;
    if (gA >= NN) gA = NN - 1;  // tail clamp; stores guarded later
    if (gB >= NN) gB = NN - 1;
    const int gMy = lo32 ? gA : gB;
    const float dMy = dinv[gMy];
    const int roA = row_off[gA], endA = row_end[gA];
    const int roB = row_off[gB], endB = row_end[gB];
    const int r = 2 * p + (lo32 ? 0 : 1);

#pragma unroll 1
    for (int h = 0; h < 2; ++h) {
      const int h32l = h * 32 + l31;
      GATHER_HALF();
      int cc = h * 64 + 2 * l31;
      float r0 = fmaxf(dMy * q0 + bias[cc], 0.f);
      float r1 = fmaxf(dMy * q1 + bias[cc + 1], 0.f);
      uint32_t pk = (uint32_t)f2bf(r0) | ((uint32_t)f2bf(r1) << 16);
      lw[r * 64 + (h32l ^ ((r & 7) << 2))] = pk;
    }
  }

  // GEMV over the wave's own 16 rows (no barrier needed).
  const int rl = lane & 15;
  const int kg = lane >> 4;
  union U { uint4 u; v8s v; };

  float di4[4];
#pragma unroll
  for (int i = 0; i < 4; ++i) {
    int node = base + kg * 4 + i;
    di4[i] = dinv[node < NN ? node : NN - 1];
  }

#pragma unroll
  for (int ct = 0; ct < 8; ++ct) {
    v4f acc = (v4f){0.f, 0.f, 0.f, 0.f};
#pragma unroll
    for (int ks = 0; ks < 4; ++ks) {
      U a, b;
      a.u = *(const uint4*)&lw[rl * 64 + ((ks * 16 + kg * 4) ^ ((rl & 7) << 2))];
      b.u = *(const uint4*)(wt + (size_t)(ct * 16 + rl) * 128 + ks * 32 + kg * 8);
      acc = __builtin_amdgcn_mfma_f32_16x16x32_bf16(a.v, b.v, acc, 0, 0, 0);
    }
#pragma unroll
    for (int i = 0; i < 4; ++i) {
      int node = base + kg * 4 + i;
      if (node < NN)
        t_out[(size_t)node * D + ct * 16 + rl] = f2bf(di4[i] * acc[i]);
    }
  }
}

// ---------------- final aggregation (f32 out), split-gather ----------------

__global__ __launch_bounds__(256) void k_agg2(
    const uint32_t* __restrict__ tu, const int* __restrict__ row_off,
    const int* __restrict__ row_end, const int* __restrict__ col,
    const float* __restrict__ dinv, const float* __restrict__ bias,
    float* __restrict__ outf) {
  const int wave = threadIdx.x >> 6;
  const int lane = threadIdx.x & 63;
  const bool lo32 = lane < 32;
  const int l31 = lane & 31;
  const int gA = blockIdx.x * 8 + wave * 2;
  const int gB = gA + 1;
  const int gMy = lo32 ? gA : gB;
  const float dMy = dinv[gMy];
  const int roA = row_off[gA], endA = row_end[gA];
  const int roB = row_off[gB], endB = row_end[gB];

#pragma unroll 1
  for (int h = 0; h < 2; ++h) {
    const int h32l = h * 32 + l31;
    GATHER_HALF();
    int cc = h * 64 + 2 * l31;
    float r0 = dMy * q0 + bias[cc];
    float r1 = dMy * q1 + bias[cc + 1];
    *(float2*)(outf + (size_t)gMy * D + cc) = make_float2(r0, r1);
  }
}

// ---------------- launch ----------------

extern "C" void kernel_launch(void* const* d_in, const int* in_sizes, int n_in,
                              void* d_out, int out_size, void* d_ws, size_t ws_size,
                              hipStream_t stream) {
  const float* x  = (const float*)d_in[0];
  const int*   ei = (const int*)d_in[1];
  const float* W1 = (const float*)d_in[2];
  const float* b1 = (const float*)d_in[3];
  const float* W2 = (const float*)d_in[4];
  const float* b2 = (const float*)d_in[5];
  const float* W3 = (const float*)d_in[6];
  const float* b3 = (const float*)d_in[7];
  float* out = (float*)d_out;

  char* base = (char*)d_ws;
  size_t o = 0;
  auto take = [&](size_t bytes) {
    void* p = base + o;
    o += (bytes + 255) & ~(size_t)255;
    return p;
  };
  int*   row_off = (int*)take((size_t)NN * 4);
  int*   row_end = (int*)take((size_t)NN * 4);
  float* dinv    = (float*)take((size_t)NN * 4);
  int*   gcur    = (int*)take((size_t)NB * 4);
  unsigned short* wt = (unsigned short*)take(3 * 16384 * 2);
  // region1: ebuf (prep, 14.4MB) -> t1 (ping-pong activations, 25.6MB)
  void* region1 = take((size_t)NN * D * 2);
  int*  col     = (int*)take((size_t)NB * BCAP * 4);
  unsigned short* t0 = (unsigned short*)take((size_t)NN * D * 2);

  uint32_t* ebuf = (uint32_t*)region1;
  unsigned short* t1 = (unsigned short*)region1;

  const int* src = ei;
  const int* dst = ei + NE;

  k_wt3z  <<<192, 256, 0, stream>>>(W1, W2, W3, wt, gcur);  // also zeroes gcur
  kb_part2<<<NPB, 256, 0, stream>>>(src, dst, gcur, ebuf);
  kb_build<<<NB, 256, 0, stream>>>(ebuf, gcur, row_off, row_end, dinv, col);

  const int gB = (NN + 127) / 128;  // 782 (2-wave blocks)
  const int fB = (NN + 31) / 32;    // 3125 (2-wave blocks, tail-guarded)
  const int aB = NN / 8;            // 12500 (exact)

  k_gemm2<<<gB, 128, 0, stream>>>(x, wt, dinv, t0);
  k_aggf<<<fB, 128, 0, stream>>>((const uint32_t*)t0, row_off, row_end, col, dinv,
                                 b1, wt + 16384, t1);
  k_aggf<<<fB, 128, 0, stream>>>((const uint32_t*)t1, row_off, row_end, col, dinv,
                                 b2, wt + 32768, t0);
  k_agg2<<<aB, 256, 0, stream>>>((const uint32_t*)t0, row_off, row_end, col, dinv,
                                 b3, out);
}

// Round 18
// 477.522 us; speedup vs baseline: 1.2607x; 1.2607x over previous
//
#include <hip/hip_runtime.h>
#include <cstddef>
#include <cstdint>

#define NN 100000
#define NE 3200000
#define D  128
#define NB 782          // ceil(NN/128) dst-buckets of 128 nodes
#define BSH 7
#define NPB 512         // partition blocks
#define CHUNK 6250      // ceil(NE/NPB)
#define BCAP 4608       // fixed bucket stride: mean 4092 + 8 sigma

typedef short v8s __attribute__((ext_vector_type(8)));
typedef float v4f __attribute__((ext_vector_type(4)));

// ---------------- bf16 helpers ----------------

__device__ __forceinline__ unsigned short f2bf(float f) {
  uint32_t u = __float_as_uint(f);
  uint32_t r = u + 0x7fff + ((u >> 16) & 1);   // RNE
  return (unsigned short)(r >> 16);
}
__device__ __forceinline__ float bf_lo(uint32_t v) {
  return __uint_as_float(v << 16);
}
__device__ __forceinline__ float bf_hi(uint32_t v) {
  return __uint_as_float(v & 0xffff0000u);
}

// ---------------- graph prep (R9-proven, exact) ----------------

__global__ __launch_bounds__(256) void kb_part2(const int* __restrict__ src,
                                                const int* __restrict__ dst,
                                                int* __restrict__ gcur,
                                                uint32_t* __restrict__ ebuf) {
  __shared__ int h[NB];
  __shared__ int cur[NB];
  for (int i = threadIdx.x; i < NB; i += 256) h[i] = 0;
  __syncthreads();
  int lo = blockIdx.x * CHUNK, hi = lo + CHUNK;
  if (hi > NE) hi = NE;
  for (int e = lo + threadIdx.x; e < hi; e += 256)
    atomicAdd(&h[dst[e] >> BSH], 1);
  __syncthreads();
  for (int i = threadIdx.x; i < NB; i += 256)
    cur[i] = h[i] ? atomicAdd(&gcur[i], h[i]) : 0;
  __syncthreads();
  for (int e = lo + threadIdx.x; e < hi; e += 256) {
    int s = src[e], d = dst[e];
    int b = d >> BSH;
    int p = atomicAdd(&cur[b], 1);
    if (p < BCAP)  // deterministic input: never triggers (8-sigma headroom)
      ebuf[(size_t)b * BCAP + p] = ((uint32_t)s << BSH) | (uint32_t)(d & 127);
  }
}

__global__ __launch_bounds__(256) void kb_build(const uint32_t* __restrict__ ebuf,
                                                const int* __restrict__ gcur,
                                                int* __restrict__ row_off,
                                                int* __restrict__ row_end,
                                                float* __restrict__ dinv,
                                                int* __restrict__ col) {
  int b = blockIdx.x;
  __shared__ int h[128];
  __shared__ int s[128];
  __shared__ int cur[128];
  if (threadIdx.x < 128) h[threadIdx.x] = 0;
  __syncthreads();
  const uint32_t* eb = ebuf + (size_t)b * BCAP;
  int cnt = gcur[b];
  for (int e = threadIdx.x; e < cnt; e += 256)
    atomicAdd(&h[eb[e] & 127], 1);
  __syncthreads();
  int v = (threadIdx.x < 128) ? h[threadIdx.x] : 0;
  if (threadIdx.x < 128) s[threadIdx.x] = v;
  __syncthreads();
  for (int d = 1; d < 128; d <<= 1) {
    int t = (threadIdx.x < 128 && threadIdx.x >= d) ? s[threadIdx.x - d] : 0;
    __syncthreads();
    if (threadIdx.x < 128) s[threadIdx.x] += t;
    __syncthreads();
  }
  if (threadIdx.x < 128) {
    int ro = b * BCAP + s[threadIdx.x] - v;
    cur[threadIdx.x] = ro;
    int node = b * 128 + threadIdx.x;
    if (node < NN) {
      row_off[node] = ro;
      row_end[node] = ro + v;
      dinv[node] = rsqrtf((float)(v + 1));  // +1 self-loop
    }
  }
  __syncthreads();
  for (int e = threadIdx.x; e < cnt; e += 256) {
    uint32_t p = eb[e];
    int pos = atomicAdd(&cur[p & 127], 1);
    col[pos] = (int)(p >> BSH);
  }
}

// ---------------- weight prep (+ gcur zeroing folded in) ----------------

__global__ void k_wt3z(const float* __restrict__ W1, const float* __restrict__ W2,
                       const float* __restrict__ W3, unsigned short* __restrict__ wt,
                       int* __restrict__ gcur) {
  int idx = blockIdx.x * 256 + threadIdx.x;  // 0..49151
  if (idx < NB) gcur[idx] = 0;
  if (idx >= 3 * 16384) return;
  int m = idx >> 14, rem = idx & 16383;
  int k = rem >> 7, c = rem & 127;
  const float* W = (m == 0) ? W1 : (m == 1) ? W2 : W3;
  wt[m * 16384 + c * 128 + k] = f2bf(W[rem]);
}

// ---------------- MFMA GEMM for layer 1 (f32 x input; R6-proven math) ----------------
// 128 threads / 2 waves per block (finer grid, less end-of-grid tail).

__global__ __launch_bounds__(128) void k_gemm2(const float* __restrict__ A,
                                               const unsigned short* __restrict__ wt,
                                               const float* __restrict__ dinv,
                                               unsigned short* __restrict__ C) {
  const int wave = threadIdx.x >> 6;
  const int lane = threadIdx.x & 63;
  const int row0 = blockIdx.x * 128 + wave * 64;
  const int rl = lane & 15;
  const int kg = lane >> 4;

  v4f acc[4][8];
#pragma unroll
  for (int t = 0; t < 4; ++t)
#pragma unroll
    for (int ct = 0; ct < 8; ++ct) acc[t][ct] = (v4f){0.f, 0.f, 0.f, 0.f};

  union U { uint4 u; v8s v; unsigned short us[8]; };

#pragma unroll
  for (int ks = 0; ks < 4; ++ks) {
    U a[4];
#pragma unroll
    for (int t = 0; t < 4; ++t) {
      int r = row0 + t * 16 + rl;
      if (r >= NN) r = NN - 1;   // clamp; stores guarded
      const float* ap = A + (size_t)r * D + ks * 32 + kg * 8;
      float4 l4 = *(const float4*)ap;
      float4 h4 = *(const float4*)(ap + 4);
      a[t].us[0] = f2bf(l4.x); a[t].us[1] = f2bf(l4.y);
      a[t].us[2] = f2bf(l4.z); a[t].us[3] = f2bf(l4.w);
      a[t].us[4] = f2bf(h4.x); a[t].us[5] = f2bf(h4.y);
      a[t].us[6] = f2bf(h4.z); a[t].us[7] = f2bf(h4.w);
    }
#pragma unroll
    for (int ct = 0; ct < 8; ++ct) {
      U b;
      b.u = *(const uint4*)(wt + (size_t)(ct * 16 + rl) * 128 + ks * 32 + kg * 8);
#pragma unroll
      for (int t = 0; t < 4; ++t)
        acc[t][ct] =
            __builtin_amdgcn_mfma_f32_16x16x32_bf16(a[t].v, b.v, acc[t][ct], 0, 0, 0);
    }
  }

#pragma unroll
  for (int t = 0; t < 4; ++t) {
#pragma unroll
    for (int i = 0; i < 4; ++i) {
      int row = row0 + t * 16 + kg * 4 + i;
      if (row < NN) {
        float dv = dinv[row];
#pragma unroll
        for (int ct = 0; ct < 8; ++ct)
          C[(size_t)row * D + ct * 16 + rl] = f2bf(dv * acc[t][ct][i]);
      }
    }
  }
}

// ---------------- gather macros (R14-exact) ----------------

#define AGG8(e0, q0, q1)                                     \
  {                                                          \
    int s0 = col[e0], s1 = col[e0 + 1], s2 = col[e0 + 2],    \
        s3 = col[e0 + 3], s4 = col[e0 + 4], s5 = col[e0 + 5],\
        s6 = col[e0 + 6], s7 = col[e0 + 7];                  \
    uint32_t v0 = tu[(size_t)s0 * 64 + lane];                \
    uint32_t v1 = tu[(size_t)s1 * 64 + lane];                \
    uint32_t v2 = tu[(size_t)s2 * 64 + lane];                \
    uint32_t v3 = tu[(size_t)s3 * 64 + lane];                \
    uint32_t v4 = tu[(size_t)s4 * 64 + lane];                \
    uint32_t v5 = tu[(size_t)s5 * 64 + lane];                \
    uint32_t v6 = tu[(size_t)s6 * 64 + lane];                \
    uint32_t v7 = tu[(size_t)s7 * 64 + lane];                \
    q0 += bf_lo(v0); q1 += bf_hi(v0);                        \
    q0 += bf_lo(v1); q1 += bf_hi(v1);                        \
    q0 += bf_lo(v2); q1 += bf_hi(v2);                        \
    q0 += bf_lo(v3); q1 += bf_hi(v3);                        \
    q0 += bf_lo(v4); q1 += bf_hi(v4);                        \
    q0 += bf_lo(v5); q1 += bf_hi(v5);                        \
    q0 += bf_lo(v6); q1 += bf_hi(v6);                        \
    q0 += bf_lo(v7); q1 += bf_hi(v7);                        \
  }

// dual-node gather producing a0,a1,b0,b1 for nodes gA,gB
#define GATHER_BODY()                                                        \
  uint32_t svA = tu[(size_t)gA * 64 + lane];                                 \
  uint32_t svB = tu[(size_t)gB * 64 + lane];                                 \
  float a0 = bf_lo(svA), a1 = bf_hi(svA);                                    \
  float b0 = bf_lo(svB), b1 = bf_hi(svB);                                    \
  int eA = row_off[gA], endA = row_end[gA];                                  \
  int eB = row_off[gB], endB = row_end[gB];                                  \
  while (eA + 8 <= endA && eB + 8 <= endB) {                                 \
    int sA0 = col[eA],     sA1 = col[eA + 1], sA2 = col[eA + 2],             \
        sA3 = col[eA + 3], sA4 = col[eA + 4], sA5 = col[eA + 5],             \
        sA6 = col[eA + 6], sA7 = col[eA + 7];                                \
    int sB0 = col[eB],     sB1 = col[eB + 1], sB2 = col[eB + 2],             \
        sB3 = col[eB + 3], sB4 = col[eB + 4], sB5 = col[eB + 5],             \
        sB6 = col[eB + 6], sB7 = col[eB + 7];                                \
    uint32_t vA0 = tu[(size_t)sA0 * 64 + lane];                              \
    uint32_t vA1 = tu[(size_t)sA1 * 64 + lane];                              \
    uint32_t vA2 = tu[(size_t)sA2 * 64 + lane];                              \
    uint32_t vA3 = tu[(size_t)sA3 * 64 + lane];                              \
    uint32_t vA4 = tu[(size_t)sA4 * 64 + lane];                              \
    uint32_t vA5 = tu[(size_t)sA5 * 64 + lane];                              \
    uint32_t vA6 = tu[(size_t)sA6 * 64 + lane];                              \
    uint32_t vA7 = tu[(size_t)sA7 * 64 + lane];                              \
    uint32_t vB0 = tu[(size_t)sB0 * 64 + lane];                              \
    uint32_t vB1 = tu[(size_t)sB1 * 64 + lane];                              \
    uint32_t vB2 = tu[(size_t)sB2 * 64 + lane];                              \
    uint32_t vB3 = tu[(size_t)sB3 * 64 + lane];                              \
    uint32_t vB4 = tu[(size_t)sB4 * 64 + lane];                              \
    uint32_t vB5 = tu[(size_t)sB5 * 64 + lane];                              \
    uint32_t vB6 = tu[(size_t)sB6 * 64 + lane];                              \
    uint32_t vB7 = tu[(size_t)sB7 * 64 + lane];                              \
    a0 += bf_lo(vA0); a1 += bf_hi(vA0);                                      \
    a0 += bf_lo(vA1); a1 += bf_hi(vA1);                                      \
    a0 += bf_lo(vA2); a1 += bf_hi(vA2);                                      \
    a0 += bf_lo(vA3); a1 += bf_hi(vA3);                                      \
    a0 += bf_lo(vA4); a1 += bf_hi(vA4);                                      \
    a0 += bf_lo(vA5); a1 += bf_hi(vA5);                                      \
    a0 += bf_lo(vA6); a1 += bf_hi(vA6);                                      \
    a0 += bf_lo(vA7); a1 += bf_hi(vA7);                                      \
    b0 += bf_lo(vB0); b1 += bf_hi(vB0);                                      \
    b0 += bf_lo(vB1); b1 += bf_hi(vB1);                                      \
    b0 += bf_lo(vB2); b1 += bf_hi(vB2);                                      \
    b0 += bf_lo(vB3); b1 += bf_hi(vB3);                                      \
    b0 += bf_lo(vB4); b1 += bf_hi(vB4);                                      \
    b0 += bf_lo(vB5); b1 += bf_hi(vB5);                                      \
    b0 += bf_lo(vB6); b1 += bf_hi(vB6);                                      \
    b0 += bf_lo(vB7); b1 += bf_hi(vB7);                                      \
    eA += 8; eB += 8;                                                        \
  }                                                                          \
  for (; eA + 8 <= endA; eA += 8) AGG8(eA, a0, a1);                          \
  for (; eA < endA; ++eA) {                                                  \
    uint32_t v = tu[(size_t)col[eA] * 64 + lane];                            \
    a0 += bf_lo(v); a1 += bf_hi(v);                                          \
  }                                                                          \
  for (; eB + 8 <= endB; eB += 8) AGG8(eB, b0, b1);                          \
  for (; eB < endB; ++eB) {                                                  \
    uint32_t v = tu[(size_t)col[eB] * 64 + lane];                            \
    b0 += bf_lo(v); b1 += bf_hi(v);                                          \
  }

// ---------------- fused agg + GEMV, barrier-free (R14 math, finer grid) ----------------
// 128 threads / 2 waves per block, 16 nodes per wave -> 3125 blocks
// (12.2/CU). Per-wave instruction stream identical to R14 -> absmax bit-exact.

__global__ __launch_bounds__(128) void k_aggf(
    const uint32_t* __restrict__ tu, const int* __restrict__ row_off,
    const int* __restrict__ row_end, const int* __restrict__ col,
    const float* __restrict__ dinv, const float* __restrict__ bias,
    const unsigned short* __restrict__ wt, unsigned short* __restrict__ t_out) {
  const int wave = threadIdx.x >> 6;
  const int lane = threadIdx.x & 63;
  const int base = blockIdx.x * 32 + wave * 16;  // this wave's 16 nodes

  __shared__ uint32_t lds[2][16 * 64];  // 4KB per wave, private slices
  uint32_t* lw = lds[wave];

  const int c = lane * 2;
  const float bl = bias[c], bh = bias[c + 1];

#pragma unroll 1
  for (int p = 0; p < 8; ++p) {
    int gA = base + 2 * p;
    int gB = gA + 1;
    if (gA >= NN) gA = NN - 1;  // tail clamp; stores guarded later
    if (gB >= NN) gB = NN - 1;
    const float diA = dinv[gA], diB = dinv[gB];

    GATHER_BODY();

    uint32_t packA = (uint32_t)f2bf(fmaxf(diA * a0 + bl, 0.f)) |
                     ((uint32_t)f2bf(fmaxf(diA * a1 + bh, 0.f)) << 16);
    uint32_t packB = (uint32_t)f2bf(fmaxf(diB * b0 + bl, 0.f)) |
                     ((uint32_t)f2bf(fmaxf(diB * b1 + bh, 0.f)) << 16);
    const int rA = 2 * p, rB = rA + 1;
    lw[rA * 64 + (lane ^ ((rA & 7) << 2))] = packA;
    lw[rB * 64 + (lane ^ ((rB & 7) << 2))] = packB;
  }

  // GEMV over the wave's own 16 rows (no barrier needed).
  const int rl = lane & 15;
  const int kg = lane >> 4;
  union U { uint4 u; v8s v; };

  float di4[4];
#pragma unroll
  for (int i = 0; i < 4; ++i) {
    int node = base + kg * 4 + i;
    di4[i] = dinv[node < NN ? node : NN - 1];
  }

#pragma unroll
  for (int ct = 0; ct < 8; ++ct) {
    v4f acc = (v4f){0.f, 0.f, 0.f, 0.f};
#pragma unroll
    for (int ks = 0; ks < 4; ++ks) {
      U a, b;
      a.u = *(const uint4*)&lw[rl * 64 + ((ks * 16 + kg * 4) ^ ((rl & 7) << 2))];
      b.u = *(const uint4*)(wt + (size_t)(ct * 16 + rl) * 128 + ks * 32 + kg * 8);
      acc = __builtin_amdgcn_mfma_f32_16x16x32_bf16(a.v, b.v, acc, 0, 0, 0);
    }
#pragma unroll
    for (int i = 0; i < 4; ++i) {
      int node = base + kg * 4 + i;
      if (node < NN)
        t_out[(size_t)node * D + ct * 16 + rl] = f2bf(di4[i] * acc[i]);
    }
  }
}

// ---------------- final aggregation (f32 out; R9 structure) ----------------

__global__ __launch_bounds__(256) void k_agg2(
    const uint32_t* __restrict__ tu, const int* __restrict__ row_off,
    const int* __restrict__ row_end, const int* __restrict__ col,
    const float* __restrict__ dinv, const float* __restrict__ bias,
    float* __restrict__ outf) {
  const int wave = threadIdx.x >> 6;
  const int lane = threadIdx.x & 63;
  const int gA = blockIdx.x * 8 + wave * 2;
  const int gB = gA + 1;

  const float diA = dinv[gA], diB = dinv[gB];

  GATHER_BODY();

  int c = lane * 2;
  float rA0 = diA * a0 + bias[c];
  float rA1 = diA * a1 + bias[c + 1];
  float rB0 = diB * b0 + bias[c];
  float rB1 = diB * b1 + bias[c + 1];
  *(float2*)(outf + (size_t)gA * D + c) = make_float2(rA0, rA1);
  *(float2*)(outf + (size_t)gB * D + c) = make_float2(rB0, rB1);
}

// ---------------- launch ----------------

extern "C" void kernel_launch(void* const* d_in, const int* in_sizes, int n_in,
                              void* d_out, int out_size, void* d_ws, size_t ws_size,
                              hipStream_t stream) {
  const float* x  = (const float*)d_in[0];
  const int*   ei = (const int*)d_in[1];
  const float* W1 = (const float*)d_in[2];
  const float* b1 = (const float*)d_in[3];
  const float* W2 = (const float*)d_in[4];
  const float* b2 = (const float*)d_in[5];
  const float* W3 = (const float*)d_in[6];
  const float* b3 = (const float*)d_in[7];
  float* out = (float*)d_out;

  char* base = (char*)d_ws;
  size_t o = 0;
  auto take = [&](size_t bytes) {
    void* p = base + o;
    o += (bytes + 255) & ~(size_t)255;
    return p;
  };
  int*   row_off = (int*)take((size_t)NN * 4);
  int*   row_end = (int*)take((size_t)NN * 4);
  float* dinv    = (float*)take((size_t)NN * 4);
  int*   gcur    = (int*)take((size_t)NB * 4);
  unsigned short* wt = (unsigned short*)take(3 * 16384 * 2);
  // region1: ebuf (prep, 14.4MB) -> t1 (ping-pong activations, 25.6MB)
  void* region1 = take((size_t)NN * D * 2);
  int*  col     = (int*)take((size_t)NB * BCAP * 4);
  unsigned short* t0 = (unsigned short*)take((size_t)NN * D * 2);

  uint32_t* ebuf = (uint32_t*)region1;
  unsigned short* t1 = (unsigned short*)region1;

  const int* src = ei;
  const int* dst = ei + NE;

  k_wt3z  <<<192, 256, 0, stream>>>(W1, W2, W3, wt, gcur);  // also zeroes gcur
  kb_part2<<<NPB, 256, 0, stream>>>(src, dst, gcur, ebuf);
  kb_build<<<NB, 256, 0, stream>>>(ebuf, gcur, row_off, row_end, dinv, col);

  const int gB = (NN + 127) / 128;  // 782 (2-wave blocks)
  const int fB = (NN + 31) / 32;    // 3125 (2-wave blocks, tail-guarded)
  const int aB = NN / 8;            // 12500 (exact)

  k_gemm2<<<gB, 128, 0, stream>>>(x, wt, dinv, t0);
  k_aggf<<<fB, 128, 0, stream>>>((const uint32_t*)t0, row_off, row_end, col, dinv,
                                 b1, wt + 16384, t1);
  k_aggf<<<fB, 128, 0, stream>>>((const uint32_t*)t1, row_off, row_end, col, dinv,
                                 b2, wt + 32768, t0);
  k_agg2<<<aB, 256, 0, stream>>>((const uint32_t*)t0, row_off, row_end, col, dinv,
                                 b3, out);
}